// Round 1
// baseline (135.582 us; speedup 1.0000x reference)
//
#include <hip/hip_runtime.h>
#include <stdint.h>

// BlockAttention: B=8, S=8192, D=H=128, BLOCK=256, WINDOW=256 (halo 255, W=766)
// No softmax => out_blk = Q_blk @ (scale * M_n),  M_n = K_win^T V_win.
// Window decomposition: M_n = C_{n-1} + C_n + C_{n+1} - k_a(x)v_a - k_z(x)v_z
//   C_m = sum over block m's 256 keys of k(x)v ;  a=(n-1)*256, z=(n+1)*256+255.
// proj:   x -> q bf16 [b][s][d], kt bf16 [b][d][s], vt bf16 [b][h][s] + edge rows
// chunkc: per (b,n): C_n^T[h][d] f32 via direct global->MFMA (no LDS, 1 pass/key)
// attn:   M^T = sum(3 C) - rank-1 edges, then O = Q * M (unchanged O-phase).

#define B_ 8
#define S_ 8192

using bf16x8 = __attribute__((ext_vector_type(8))) short;   // 8 bf16 = 4 VGPRs
using s16x4  = __attribute__((ext_vector_type(4))) short;
using f32x16 = __attribute__((ext_vector_type(16))) float;

__device__ __forceinline__ short f2bf(float f) {
  union { float f; uint32_t u; } v; v.f = f;
  uint32_t r = v.u + 0x7fffu + ((v.u >> 16) & 1u);   // RNE
  return (short)(r >> 16);
}
__device__ __forceinline__ float bf2f(short s) {
  union { uint32_t u; float f; } v; v.u = ((uint32_t)(uint16_t)s) << 16;
  return v.f;
}

// ---------------------------------------------------------------------------
// Projection: 512 blocks x 256 threads, 128 rows (b*S+s) per block.
// ---------------------------------------------------------------------------
#define LDW 136   // padded leading dim (bf16 elems) for 128-wide LDS tiles

__global__ __launch_bounds__(256) void proj_kernel(
    const float* __restrict__ x,
    const float* __restrict__ Wq, const float* __restrict__ bq,
    const float* __restrict__ Wk, const float* __restrict__ bk,
    const float* __restrict__ Wv, const float* __restrict__ bv,
    short* __restrict__ qb, short* __restrict__ ktb, short* __restrict__ vtb,
    short* __restrict__ kedge, short* __restrict__ vedge)
{
  __shared__ short wl[128 * LDW];   // 34.8 KB: weight tile / transpose tile

  const int tid  = threadIdx.x;
  const int lane = tid & 63;
  const int wv   = tid >> 6;
  const int c    = lane & 31;
  const int hl   = lane >> 5;
  const int r0   = blockIdx.x * 128;
  const int b    = r0 >> 13;
  const int s0   = r0 & (S_ - 1);

  // A fragments: A[m=lane&31][k=16*kst+8*hl+j], m-row = r0 + wv*32 + c
  bf16x8 afrag[8];
  {
    const float* xrow = x + (size_t)(r0 + wv * 32 + c) * 128 + hl * 8;
    #pragma unroll
    for (int kst = 0; kst < 8; ++kst) {
      const float4* p = (const float4*)(xrow + kst * 16);
      float4 f0 = p[0], f1 = p[1];
      bf16x8 a;
      a[0] = f2bf(f0.x); a[1] = f2bf(f0.y); a[2] = f2bf(f0.z); a[3] = f2bf(f0.w);
      a[4] = f2bf(f1.x); a[5] = f2bf(f1.y); a[6] = f2bf(f1.z); a[7] = f2bf(f1.w);
      afrag[kst] = a;
    }
  }

  auto stageW = [&](const float* W) {
    #pragma unroll
    for (int it = 0; it < 16; ++it) {
      int l  = it * 256 + tid;
      int n  = l >> 5;
      int k4 = (l & 31) << 2;
      const float4 f = *(const float4*)(W + n * 128 + k4);
      s16x4 o;
      o[0] = f2bf(f.x); o[1] = f2bf(f.y); o[2] = f2bf(f.z); o[3] = f2bf(f.w);
      *(s16x4*)(wl + n * LDW + k4) = o;
    }
  };

  auto gemm = [&](const float* bias, f32x16* acc) {
    #pragma unroll
    for (int nt = 0; nt < 4; ++nt) {
      float bvv = bias[nt * 32 + c];
      #pragma unroll
      for (int i = 0; i < 16; ++i) acc[nt][i] = bvv;
    }
    #pragma unroll
    for (int kst = 0; kst < 8; ++kst) {
      #pragma unroll
      for (int nt = 0; nt < 4; ++nt) {
        bf16x8 bb = *(const bf16x8*)(wl + (nt * 32 + c) * LDW + kst * 16 + hl * 8);
        acc[nt] = __builtin_amdgcn_mfma_f32_32x32x16_bf16(afrag[kst], bb, acc[nt], 0, 0, 0);
      }
    }
  };

  // C-tile layout: col=lane&31, row=(reg&3)+8*(reg>>2)+4*hl
  auto writeTransposedLDS = [&](f32x16* acc) {   // wl[d][s]
    #pragma unroll
    for (int nt = 0; nt < 4; ++nt) {
      int d = nt * 32 + c;
      #pragma unroll
      for (int g = 0; g < 4; ++g) {
        #pragma unroll
        for (int p = 0; p < 2; ++p) {
          int reg = g * 4 + p * 2;
          int sl  = wv * 32 + g * 8 + hl * 4 + p * 2;
          uint32_t pk = (uint32_t)(uint16_t)f2bf(acc[nt][reg]) |
                        ((uint32_t)(uint16_t)f2bf(acc[nt][reg + 1]) << 16);
          *(uint32_t*)(wl + d * LDW + sl) = pk;
        }
      }
    }
  };

  auto storeTransposed = [&](short* dst) {  // dst [b][d][s]
    #pragma unroll
    for (int it = 0; it < 8; ++it) {
      int l  = it * 256 + tid;
      int d  = l >> 4;
      int s8 = (l & 15) << 3;
      bf16x8 vv = *(const bf16x8*)(wl + d * LDW + s8);
      *(bf16x8*)(dst + ((size_t)b * 128 + d) * S_ + s0 + s8) = vv;
    }
  };

  // boundary rows of this 128-row half-block: s%256==0 (slot 0) or ==255 (slot 1)
  auto storeEdge = [&](short* edst) {
    if (tid < 128) {
      size_t eo = ((size_t)b * 32 + (s0 >> 8)) * 256;
      if ((s0 & 255) == 0) edst[eo + tid]       = wl[tid * LDW + 0];
      else                 edst[eo + 128 + tid] = wl[tid * LDW + 127];
    }
  };

  // ---- Q (row-major out, via LDS for coalesced 16B stores) ----
  stageW(Wq);
  __syncthreads();
  {
    f32x16 acc[4];
    gemm(bq, acc);
    __syncthreads();          // all waves done reading Wq from wl
    #pragma unroll
    for (int nt = 0; nt < 4; ++nt) {
      #pragma unroll
      for (int reg = 0; reg < 16; ++reg) {
        int row = (reg & 3) + 8 * (reg >> 2) + 4 * hl;
        wl[(wv * 32 + row) * LDW + nt * 32 + c] = f2bf(acc[nt][reg]);
      }
    }
    __syncthreads();
    #pragma unroll
    for (int it = 0; it < 8; ++it) {
      int l  = it * 256 + tid;
      int s  = l >> 4;
      int d8 = (l & 15) << 3;
      bf16x8 vv = *(const bf16x8*)(wl + s * LDW + d8);
      *(bf16x8*)(qb + (size_t)(r0 + s) * 128 + d8) = vv;
    }
  }
  __syncthreads();

  // ---- K (transposed out) ----
  stageW(Wk);
  __syncthreads();
  {
    f32x16 acc[4];
    gemm(bk, acc);
    __syncthreads();
    writeTransposedLDS(acc);
    __syncthreads();
    storeTransposed(ktb);
    storeEdge(kedge);
  }
  __syncthreads();

  // ---- V (transposed out) ----
  stageW(Wv);
  __syncthreads();
  {
    f32x16 acc[4];
    gemm(bv, acc);
    __syncthreads();
    writeTransposedLDS(acc);
    __syncthreads();
    storeTransposed(vtb);
    storeEdge(vedge);
  }
}

// ---------------------------------------------------------------------------
// Per-block outer-product partials: 256 blocks (b,n) x 512 threads (8 waves).
// C^T[h][d] = sum_{s in block n} V[s][h]*K[s][d], f32.  A=vt rows, B=kt rows,
// frags loaded DIRECTLY from global (ktb/vtb are [d][s] already): no LDS,
// no barriers; L1 absorbs the 64B-line sharing across kst.
// Wave grid: rowgroup = wv>>1 (4 x 32 h-rows), colhalf = wv&1 (2 x 64 d-cols).
// ---------------------------------------------------------------------------
__global__ __launch_bounds__(512) void chunkc_kernel(
    const short* __restrict__ ktb, const short* __restrict__ vtb,
    float* __restrict__ Cb)
{
  const int tid  = threadIdx.x;
  const int lane = tid & 63;
  const int wv   = tid >> 6;
  const int c    = lane & 31;
  const int hl   = lane >> 5;
  const int b    = blockIdx.x >> 5;
  const int n    = blockIdx.x & 31;
  const int s0   = n * 256;

  const short* ap = vtb + ((size_t)b * 128 + (wv >> 1) * 32 + c) * S_ + s0 + hl * 8;
  const short* bp = ktb + ((size_t)b * 128 + (wv & 1) * 64 + c) * S_ + s0 + hl * 8;

  f32x16 acc[2];
  #pragma unroll
  for (int t = 0; t < 2; ++t)
    #pragma unroll
    for (int i = 0; i < 16; ++i) acc[t][i] = 0.f;

  #pragma unroll
  for (int kst = 0; kst < 16; ++kst) {
    bf16x8 a  = *(const bf16x8*)(ap + kst * 16);
    bf16x8 b0 = *(const bf16x8*)(bp + kst * 16);
    bf16x8 b1 = *(const bf16x8*)(bp + (size_t)32 * S_ + kst * 16);
    acc[0] = __builtin_amdgcn_mfma_f32_32x32x16_bf16(a, b0, acc[0], 0, 0, 0);
    acc[1] = __builtin_amdgcn_mfma_f32_32x32x16_bf16(a, b1, acc[1], 0, 0, 0);
  }

  float* Cp = Cb + ((size_t)(b * 32 + n)) * 16384;
  #pragma unroll
  for (int t = 0; t < 2; ++t) {
    #pragma unroll
    for (int reg = 0; reg < 16; ++reg) {
      int row = (reg & 3) + 8 * (reg >> 2) + 4 * hl;
      Cp[((wv >> 1) * 32 + row) * 128 + (wv & 1) * 64 + t * 32 + c] = acc[t][reg];
    }
  }
}

// ---------------------------------------------------------------------------
// Attention: 256 blocks (b,n) x 512 threads (8 waves).
// Phase A: Mt[h][d] = scale*(C_{n-1}+C_n+C_{n+1} - v_a[h]k_a[d] - v_z[h]k_z[d])
//          thread owns (h = tid>>2, d-strip dq = (tid&3)*32); bf16 -> m_l.
// Phase B: O = Q * M (unchanged), epilogue via per-wave LDS patch.
// ---------------------------------------------------------------------------
#define LDM 136

__global__ __launch_bounds__(512) void attn_kernel(
    const short* __restrict__ qb, const float* __restrict__ Cb,
    const short* __restrict__ kedge, const short* __restrict__ vedge,
    float* __restrict__ out)
{
  __shared__ __align__(16) short m_l[128 * LDM];      // 34.8 KB
  __shared__ __align__(16) float opat[8 * 32 * 36];   // 36.9 KB

  const int tid  = threadIdx.x;
  const int lane = tid & 63;
  const int wv   = tid >> 6;
  const int c    = lane & 31;
  const int hl   = lane >> 5;
  const int b    = blockIdx.x >> 5;
  const int n    = blockIdx.x & 31;

  // ---- phase A ----
  const int h  = tid >> 2;
  const int dq = (tid & 3) << 5;

  float m[32];
  #pragma unroll
  for (int i = 0; i < 32; ++i) m[i] = 0.f;

  const float* Cbase = Cb + (size_t)b * 32 * 16384;
  #pragma unroll
  for (int dn = -1; dn <= 1; ++dn) {
    int nn = n + dn;
    if (nn < 0 || nn > 31) continue;
    const float* Cp = Cbase + (size_t)nn * 16384 + h * 128 + dq;
    #pragma unroll
    for (int i4 = 0; i4 < 8; ++i4) {
      float4 f = *(const float4*)(Cp + i4 * 4);
      m[i4 * 4 + 0] += f.x; m[i4 * 4 + 1] += f.y;
      m[i4 * 4 + 2] += f.z; m[i4 * 4 + 3] += f.w;
    }
  }
  if (n > 0) {   // subtract key a = (n-1)*256  (slot 0 of block n-1)
    const short* ke = kedge + ((size_t)(b * 32 + n - 1)) * 256;
    const short* ve = vedge + ((size_t)(b * 32 + n - 1)) * 256;
    float vs = bf2f(ve[h]);
    #pragma unroll
    for (int i8 = 0; i8 < 4; ++i8) {
      bf16x8 kr = *(const bf16x8*)(ke + dq + i8 * 8);
      #pragma unroll
      for (int j = 0; j < 8; ++j) m[i8 * 8 + j] -= vs * bf2f(kr[j]);
    }
  }
  if (n < 31) {  // subtract key z = (n+1)*256+255  (slot 1 of block n+1)
    const short* ke = kedge + ((size_t)(b * 32 + n + 1)) * 256 + 128;
    const short* ve = vedge + ((size_t)(b * 32 + n + 1)) * 256 + 128;
    float vs = bf2f(ve[h]);
    #pragma unroll
    for (int i8 = 0; i8 < 4; ++i8) {
      bf16x8 kr = *(const bf16x8*)(ke + dq + i8 * 8);
      #pragma unroll
      for (int j = 0; j < 8; ++j) m[i8 * 8 + j] -= vs * bf2f(kr[j]);
    }
  }
  const float scale = 0.08838834764831845f;   // 1/sqrt(128)
  #pragma unroll
  for (int i = 0; i < 16; ++i) {
    uint32_t pk = (uint32_t)(uint16_t)f2bf(m[2 * i] * scale) |
                  ((uint32_t)(uint16_t)f2bf(m[2 * i + 1] * scale) << 16);
    *(uint32_t*)(m_l + h * LDM + dq + 2 * i) = pk;
  }

  // Q A-frags (issue before barrier to overlap)
  bf16x8 qf[8];
  {
    const short* q0p = qb + ((size_t)b * S_ + n * 256 + wv * 32 + c) * 128 + hl * 8;
    #pragma unroll
    for (int kst = 0; kst < 8; ++kst) qf[kst] = *(const bf16x8*)(q0p + kst * 16);
  }
  __syncthreads();

  // ---- phase B: O = Q * M; wave wv owns 32 q-rows [n*256+32wv, +32) ----
  f32x16 oacc[4];
  #pragma unroll
  for (int nt = 0; nt < 4; ++nt)
    #pragma unroll
    for (int i = 0; i < 16; ++i) oacc[nt][i] = 0.f;

  #pragma unroll
  for (int kst = 0; kst < 8; ++kst) {
    #pragma unroll
    for (int nt = 0; nt < 4; ++nt) {
      bf16x8 bb = *(const bf16x8*)(m_l + (nt * 32 + c) * LDM + kst * 16 + hl * 8);
      oacc[nt] = __builtin_amdgcn_mfma_f32_32x32x16_bf16(qf[kst], bb, oacc[nt], 0, 0, 0);
    }
  }

  // epilogue: per-wave LDS patch (32x36 f32) -> coalesced float4 stores
  float* patch = opat + wv * (32 * 36);
  float* outb  = out + ((size_t)b * S_ + n * 256 + wv * 32) * 128;
  #pragma unroll
  for (int nt = 0; nt < 4; ++nt) {
    #pragma unroll
    for (int reg = 0; reg < 16; ++reg) {
      int row = (reg & 3) + 8 * (reg >> 2) + 4 * hl;
      patch[row * 36 + c] = oacc[nt][reg];
    }
    #pragma unroll
    for (int p = 0; p < 4; ++p) {
      int row = p * 8 + (lane >> 3);
      float4 vv = *(const float4*)(patch + row * 36 + (lane & 7) * 4);
      *(float4*)(outb + (size_t)row * 128 + nt * 32 + (lane & 7) * 4) = vv;
    }
  }
}

// ---------------------------------------------------------------------------
extern "C" void kernel_launch(void* const* d_in, const int* in_sizes, int n_in,
                              void* d_out, int out_size, void* d_ws, size_t ws_size,
                              hipStream_t stream) {
  const float* x  = (const float*)d_in[0];
  const float* Wq = (const float*)d_in[1];
  const float* bq = (const float*)d_in[2];
  const float* Wk = (const float*)d_in[3];
  const float* bk = (const float*)d_in[4];
  const float* Wv = (const float*)d_in[5];
  const float* bv = (const float*)d_in[6];
  float* out = (float*)d_out;

  const size_t elems = (size_t)B_ * S_ * 128;          // 8.39M per tensor
  short* qb    = (short*)d_ws;
  short* ktb   = qb + elems;
  short* vtb   = ktb + elems;
  float* Cb    = (float*)(vtb + elems);                // 8*32*128*128 f32 = 16.8MB
  short* kedge = (short*)(Cb + (size_t)8 * 32 * 16384);
  short* vedge = kedge + (size_t)8 * 32 * 256;

  proj_kernel<<<512, 256, 0, stream>>>(x, Wq, bq, Wk, bk, Wv, bv,
                                       qb, ktb, vtb, kedge, vedge);
  chunkc_kernel<<<256, 512, 0, stream>>>(ktb, vtb, Cb);
  attn_kernel<<<256, 512, 0, stream>>>(qb, Cb, kedge, vedge, out);
}

// Round 2
// 129.418 us; speedup vs baseline: 1.0476x; 1.0476x over previous
//
#include <hip/hip_runtime.h>
#include <stdint.h>

// BlockAttention: B=8, S=8192, D=H=128, BLOCK=256, WINDOW=256 (halo 255, W=766)
// No softmax => out_blk = Q_blk @ (scale * M_n),  M_n = K_win^T V_win.
// Window decomposition over 128-key HALVES:
//   M_n^T = sum_{j=2n-2}^{2n+3} Chalf_j^T - v_a(x)k_a - v_z(x)k_z
//   Chalf_j^T[h][d] = sum over half j's 128 keys of v[h]*k[d]  (f32)
//   a=(n-1)*256 (slot0 of block n-1), z=(n+1)*256+255 (slot1 of block n+1).
// proj:  x -> q bf16 [b][s][d], kt/vt bf16 [b][d][s], edge rows, AND Chalf f32
//        (C-GEMM runs on the K^T/V^T LDS tiles proj already builds -> no global
//         re-read; this replaces the former uncoalesced chunkc kernel).
// attn:  M^T = sum(6 halves, coalesced f32) - rank-1 edges, then O = Q * M.

#define B_ 8
#define S_ 8192

using bf16x8 = __attribute__((ext_vector_type(8))) short;   // 8 bf16 = 4 VGPRs
using s16x4  = __attribute__((ext_vector_type(4))) short;
using f32x16 = __attribute__((ext_vector_type(16))) float;

__device__ __forceinline__ short f2bf(float f) {
  union { float f; uint32_t u; } v; v.f = f;
  uint32_t r = v.u + 0x7fffu + ((v.u >> 16) & 1u);   // RNE
  return (short)(r >> 16);
}
__device__ __forceinline__ float bf2f(short s) {
  union { uint32_t u; float f; } v; v.u = ((uint32_t)(uint16_t)s) << 16;
  return v.f;
}

// ---------------------------------------------------------------------------
// Projection + C-halves: 512 blocks x 256 threads, 128 rows (b*S+s) per block.
// ---------------------------------------------------------------------------
#define LDW 136   // padded leading dim (bf16 elems) for 128-wide LDS tiles

__global__ __launch_bounds__(256) void proj_kernel(
    const float* __restrict__ x,
    const float* __restrict__ Wq, const float* __restrict__ bq,
    const float* __restrict__ Wk, const float* __restrict__ bk,
    const float* __restrict__ Wv, const float* __restrict__ bv,
    short* __restrict__ qb, short* __restrict__ ktb, short* __restrict__ vtb,
    short* __restrict__ kedge, short* __restrict__ vedge,
    float* __restrict__ Cpart)
{
  __shared__ short wlA[128 * LDW];   // 34.8 KB: weights / K^T tile / Q tile
  __shared__ short wlB[128 * LDW];   // 34.8 KB: weights / V^T tile

  const int tid  = threadIdx.x;
  const int lane = tid & 63;
  const int wv   = tid >> 6;
  const int c    = lane & 31;
  const int hl   = lane >> 5;
  const int r0   = blockIdx.x * 128;
  const int b    = r0 >> 13;
  const int s0   = r0 & (S_ - 1);

  // A fragments: A[m=lane&31][k=16*kst+8*hl+j], m-row = r0 + wv*32 + c
  bf16x8 afrag[8];
  {
    const float* xrow = x + (size_t)(r0 + wv * 32 + c) * 128 + hl * 8;
    #pragma unroll
    for (int kst = 0; kst < 8; ++kst) {
      const float4* p = (const float4*)(xrow + kst * 16);
      float4 f0 = p[0], f1 = p[1];
      bf16x8 a;
      a[0] = f2bf(f0.x); a[1] = f2bf(f0.y); a[2] = f2bf(f0.z); a[3] = f2bf(f0.w);
      a[4] = f2bf(f1.x); a[5] = f2bf(f1.y); a[6] = f2bf(f1.z); a[7] = f2bf(f1.w);
      afrag[kst] = a;
    }
  }

  auto stageW = [&](const float* W, short* wl) {
    #pragma unroll
    for (int it = 0; it < 16; ++it) {
      int l  = it * 256 + tid;
      int n  = l >> 5;
      int k4 = (l & 31) << 2;
      const float4 f = *(const float4*)(W + n * 128 + k4);
      s16x4 o;
      o[0] = f2bf(f.x); o[1] = f2bf(f.y); o[2] = f2bf(f.z); o[3] = f2bf(f.w);
      *(s16x4*)(wl + n * LDW + k4) = o;
    }
  };

  auto gemm = [&](const float* bias, f32x16* acc, const short* wl) {
    #pragma unroll
    for (int nt = 0; nt < 4; ++nt) {
      float bvv = bias[nt * 32 + c];
      #pragma unroll
      for (int i = 0; i < 16; ++i) acc[nt][i] = bvv;
    }
    #pragma unroll
    for (int kst = 0; kst < 8; ++kst) {
      #pragma unroll
      for (int nt = 0; nt < 4; ++nt) {
        bf16x8 bb = *(const bf16x8*)(wl + (nt * 32 + c) * LDW + kst * 16 + hl * 8);
        acc[nt] = __builtin_amdgcn_mfma_f32_32x32x16_bf16(afrag[kst], bb, acc[nt], 0, 0, 0);
      }
    }
  };

  // C-tile layout: col=lane&31, row=(reg&3)+8*(reg>>2)+4*hl
  auto writeTransposedLDS = [&](f32x16* acc, short* wl) {   // wl[d][s]
    #pragma unroll
    for (int nt = 0; nt < 4; ++nt) {
      int d = nt * 32 + c;
      #pragma unroll
      for (int g = 0; g < 4; ++g) {
        #pragma unroll
        for (int p = 0; p < 2; ++p) {
          int reg = g * 4 + p * 2;
          int sl  = wv * 32 + g * 8 + hl * 4 + p * 2;
          uint32_t pk = (uint32_t)(uint16_t)f2bf(acc[nt][reg]) |
                        ((uint32_t)(uint16_t)f2bf(acc[nt][reg + 1]) << 16);
          *(uint32_t*)(wl + d * LDW + sl) = pk;
        }
      }
    }
  };

  auto storeTransposed = [&](short* dst, const short* wl) {  // dst [b][d][s]
    #pragma unroll
    for (int it = 0; it < 8; ++it) {
      int l  = it * 256 + tid;
      int d  = l >> 4;
      int s8 = (l & 15) << 3;
      bf16x8 vv = *(const bf16x8*)(wl + d * LDW + s8);
      *(bf16x8*)(dst + ((size_t)b * 128 + d) * S_ + s0 + s8) = vv;
    }
  };

  // boundary rows: s%256==0 (slot 0) or s%256==255 (slot 1) of block s/256
  auto storeEdge = [&](short* edst, const short* wl) {
    if (tid < 128) {
      size_t eo = ((size_t)b * 32 + (s0 >> 8)) * 256;
      if ((s0 & 255) == 0) edst[eo + tid]       = wl[tid * LDW + 0];
      else                 edst[eo + 128 + tid] = wl[tid * LDW + 127];
    }
  };

  // ---- K (transposed out, tile kept in wlA) ----
  stageW(Wk, wlA);
  __syncthreads();
  {
    f32x16 acc[4];
    gemm(bk, acc, wlA);
    __syncthreads();                 // all waves done reading Wk from wlA
    writeTransposedLDS(acc, wlA);    // K^T -> wlA
    __syncthreads();
    storeTransposed(ktb, wlA);
    storeEdge(kedge, wlA);
  }

  // ---- V (transposed out, tile kept in wlB) ----
  stageW(Wv, wlB);                   // writes wlB only; reads of wlA above are fine
  __syncthreads();
  {
    f32x16 acc[4];
    gemm(bv, acc, wlB);
    __syncthreads();                 // done reading Wv from wlB
    writeTransposedLDS(acc, wlB);    // V^T -> wlB  (K^T still live in wlA)
    __syncthreads();
    storeTransposed(vtb, wlB);
    storeEdge(vedge, wlB);
  }

  // ---- C-half GEMM: Chalf^T[h][d] = sum_s V^T[h][s] * K^T[d][s]  (f32) ----
  // A-frags from wlB (V^T, rows h = wv*32+c), B-frags from wlA (K^T, rows d).
  // Reads only; both tiles stable since their last barrier.
  {
    f32x16 cacc[4];
    #pragma unroll
    for (int nt = 0; nt < 4; ++nt)
      #pragma unroll
      for (int i = 0; i < 16; ++i) cacc[nt][i] = 0.f;

    #pragma unroll
    for (int kst = 0; kst < 8; ++kst) {
      bf16x8 a = *(const bf16x8*)(wlB + (wv * 32 + c) * LDW + kst * 16 + hl * 8);
      #pragma unroll
      for (int nt = 0; nt < 4; ++nt) {
        bf16x8 bb = *(const bf16x8*)(wlA + (nt * 32 + c) * LDW + kst * 16 + hl * 8);
        cacc[nt] = __builtin_amdgcn_mfma_f32_32x32x16_bf16(a, bb, cacc[nt], 0, 0, 0);
      }
    }

    float* Cp = Cpart + ((size_t)b * 64 + (s0 >> 7)) * 16384;
    #pragma unroll
    for (int nt = 0; nt < 4; ++nt) {
      #pragma unroll
      for (int reg = 0; reg < 16; ++reg) {
        int row = (reg & 3) + 8 * (reg >> 2) + 4 * hl;
        Cp[(wv * 32 + row) * 128 + nt * 32 + c] = cacc[nt][reg];
      }
    }
  }
  __syncthreads();                   // done reading wlA/wlB before reuse

  // ---- Q (row-major out, via LDS for coalesced 16B stores) ----
  stageW(Wq, wlA);
  __syncthreads();
  {
    f32x16 acc[4];
    gemm(bq, acc, wlA);
    __syncthreads();                 // all waves done reading Wq from wlA
    #pragma unroll
    for (int nt = 0; nt < 4; ++nt) {
      #pragma unroll
      for (int reg = 0; reg < 16; ++reg) {
        int row = (reg & 3) + 8 * (reg >> 2) + 4 * hl;
        wlA[(wv * 32 + row) * LDW + nt * 32 + c] = f2bf(acc[nt][reg]);
      }
    }
    __syncthreads();
    #pragma unroll
    for (int it = 0; it < 8; ++it) {
      int l  = it * 256 + tid;
      int s  = l >> 4;
      int d8 = (l & 15) << 3;
      bf16x8 vv = *(const bf16x8*)(wlA + s * LDW + d8);
      *(bf16x8*)(qb + (size_t)(r0 + s) * 128 + d8) = vv;
    }
  }
}

// ---------------------------------------------------------------------------
// Attention: 256 blocks (b,n) x 512 threads (8 waves).
// Phase A: M^T[h][d] = scale*(sum of 6 C-halves - v_a[h]k_a[d] - v_z[h]k_z[d])
//   Thread-linear ownership: thread owns 8 float4s at float4-index i4*512+tid
//   -> fully coalesced 8KB/wave-instruction loads of each C-half.
//   Owned element group i4: h = i4*16 + (tid>>5), d = (tid&31)*4 .. +3.
// Phase B: O = Q * M (LDS-staged M^T, bf16), epilogue via per-wave LDS patch.
// ---------------------------------------------------------------------------
#define LDM 136

__global__ __launch_bounds__(512) void attn_kernel(
    const short* __restrict__ qb, const float* __restrict__ Cpart,
    const short* __restrict__ kedge, const short* __restrict__ vedge,
    float* __restrict__ out)
{
  __shared__ __align__(16) short m_l[128 * LDM];      // 34.8 KB
  __shared__ __align__(16) float opat[8 * 32 * 36];   // 36.9 KB

  const int tid  = threadIdx.x;
  const int lane = tid & 63;
  const int wv   = tid >> 6;
  const int c    = lane & 31;
  const int hl   = lane >> 5;
  const int b    = blockIdx.x >> 5;
  const int n    = blockIdx.x & 31;

  // ---- phase A ----
  float m[32];
  #pragma unroll
  for (int i = 0; i < 32; ++i) m[i] = 0.f;

  const float* Cb0 = Cpart + (size_t)b * 64 * 16384;
  #pragma unroll
  for (int e = 0; e < 6; ++e) {
    int hj = 2 * n - 2 + e;
    if (hj < 0 || hj >= 64) continue;        // wave-uniform branch
    const float4* Cp = (const float4*)(Cb0 + (size_t)hj * 16384);
    #pragma unroll
    for (int i4 = 0; i4 < 8; ++i4) {
      float4 f = Cp[i4 * 512 + tid];
      m[i4 * 4 + 0] += f.x; m[i4 * 4 + 1] += f.y;
      m[i4 * 4 + 2] += f.z; m[i4 * 4 + 3] += f.w;
    }
  }

  const int d0 = (tid & 31) << 2;
  if (n > 0) {   // subtract key a = (n-1)*256  (slot 0 of block n-1)
    const short* ke = kedge + ((size_t)(b * 32 + n - 1)) * 256;
    const short* ve = vedge + ((size_t)(b * 32 + n - 1)) * 256;
    float k0 = bf2f(ke[d0]),     k1 = bf2f(ke[d0 + 1]);
    float k2 = bf2f(ke[d0 + 2]), k3 = bf2f(ke[d0 + 3]);
    #pragma unroll
    for (int i4 = 0; i4 < 8; ++i4) {
      float vs = bf2f(ve[i4 * 16 + (tid >> 5)]);
      m[i4 * 4 + 0] -= vs * k0; m[i4 * 4 + 1] -= vs * k1;
      m[i4 * 4 + 2] -= vs * k2; m[i4 * 4 + 3] -= vs * k3;
    }
  }
  if (n < 31) {  // subtract key z = (n+1)*256+255  (slot 1 of block n+1)
    const short* ke = kedge + ((size_t)(b * 32 + n + 1)) * 256 + 128;
    const short* ve = vedge + ((size_t)(b * 32 + n + 1)) * 256 + 128;
    float k0 = bf2f(ke[d0]),     k1 = bf2f(ke[d0 + 1]);
    float k2 = bf2f(ke[d0 + 2]), k3 = bf2f(ke[d0 + 3]);
    #pragma unroll
    for (int i4 = 0; i4 < 8; ++i4) {
      float vs = bf2f(ve[i4 * 16 + (tid >> 5)]);
      m[i4 * 4 + 0] -= vs * k0; m[i4 * 4 + 1] -= vs * k1;
      m[i4 * 4 + 2] -= vs * k2; m[i4 * 4 + 3] -= vs * k3;
    }
  }

  const float scale = 0.08838834764831845f;   // 1/sqrt(128)
  #pragma unroll
  for (int i4 = 0; i4 < 8; ++i4) {
    int h = i4 * 16 + (tid >> 5);
    s16x4 o;
    o[0] = f2bf(m[i4 * 4 + 0] * scale); o[1] = f2bf(m[i4 * 4 + 1] * scale);
    o[2] = f2bf(m[i4 * 4 + 2] * scale); o[3] = f2bf(m[i4 * 4 + 3] * scale);
    *(s16x4*)(m_l + h * LDM + d0) = o;
  }

  // Q A-frags (issue before barrier to overlap)
  bf16x8 qf[8];
  {
    const short* q0p = qb + ((size_t)b * S_ + n * 256 + wv * 32 + c) * 128 + hl * 8;
    #pragma unroll
    for (int kst = 0; kst < 8; ++kst) qf[kst] = *(const bf16x8*)(q0p + kst * 16);
  }
  __syncthreads();

  // ---- phase B: O = Q * M; wave wv owns 32 q-rows [n*256+32wv, +32) ----
  f32x16 oacc[4];
  #pragma unroll
  for (int nt = 0; nt < 4; ++nt)
    #pragma unroll
    for (int i = 0; i < 16; ++i) oacc[nt][i] = 0.f;

  #pragma unroll
  for (int kst = 0; kst < 8; ++kst) {
    #pragma unroll
    for (int nt = 0; nt < 4; ++nt) {
      bf16x8 bb = *(const bf16x8*)(m_l + (nt * 32 + c) * LDM + kst * 16 + hl * 8);
      oacc[nt] = __builtin_amdgcn_mfma_f32_32x32x16_bf16(qf[kst], bb, oacc[nt], 0, 0, 0);
    }
  }

  // epilogue: per-wave LDS patch (32x36 f32) -> coalesced float4 stores
  float* patch = opat + wv * (32 * 36);
  float* outb  = out + ((size_t)b * S_ + n * 256 + wv * 32) * 128;
  #pragma unroll
  for (int nt = 0; nt < 4; ++nt) {
    #pragma unroll
    for (int reg = 0; reg < 16; ++reg) {
      int row = (reg & 3) + 8 * (reg >> 2) + 4 * hl;
      patch[row * 36 + c] = oacc[nt][reg];
    }
    #pragma unroll
    for (int p = 0; p < 4; ++p) {
      int row = p * 8 + (lane >> 3);
      float4 vv = *(const float4*)(patch + row * 36 + (lane & 7) * 4);
      *(float4*)(outb + (size_t)row * 128 + nt * 32 + (lane & 7) * 4) = vv;
    }
  }
}

// ---------------------------------------------------------------------------
extern "C" void kernel_launch(void* const* d_in, const int* in_sizes, int n_in,
                              void* d_out, int out_size, void* d_ws, size_t ws_size,
                              hipStream_t stream) {
  const float* x  = (const float*)d_in[0];
  const float* Wq = (const float*)d_in[1];
  const float* bq = (const float*)d_in[2];
  const float* Wk = (const float*)d_in[3];
  const float* bk = (const float*)d_in[4];
  const float* Wv = (const float*)d_in[5];
  const float* bv = (const float*)d_in[6];
  float* out = (float*)d_out;

  const size_t elems = (size_t)B_ * S_ * 128;          // 8.39M per tensor
  short* qb    = (short*)d_ws;
  short* ktb   = qb + elems;
  short* vtb   = ktb + elems;
  float* Cpart = (float*)(vtb + elems);                // 8*64*128*128 f32 = 33.6MB
  short* kedge = (short*)(Cpart + (size_t)8 * 64 * 16384);
  short* vedge = kedge + (size_t)8 * 32 * 256;

  proj_kernel<<<512, 256, 0, stream>>>(x, Wq, bq, Wk, bk, Wv, bv,
                                       qb, ktb, vtb, kedge, vedge, Cpart);
  attn_kernel<<<256, 512, 0, stream>>>(qb, Cpart, kedge, vedge, out);
}

// Round 3
// 120.377 us; speedup vs baseline: 1.1263x; 1.0751x over previous
//
#include <hip/hip_runtime.h>
#include <stdint.h>

// BlockAttention: B=8, S=8192, D=H=128, BLOCK=256, WINDOW=256 (halo 255, W=766)
// No softmax => out_blk = Q_blk @ (scale * M_n),  M_n = K_win^T V_win.
// Full-block decomposition:
//   M_n^T = C_{n-1}^T + C_n^T + C_{n+1}^T - v_a(x)k_a - v_z(x)k_z
//   C_m^T[h][d] = sum over block m's 256 keys of v[h]*k[d]  (f32)
//   a = (n-1)*256 (slot0 of block n-1), z = (n+1)*256+255 (slot1 of block n+1).
// kv_kernel:    per (b,n): K/V proj (LDS tiles only, no global K/V tensors!),
//               C_n^T via LDS-tile GEMM over 256 keys, + 2 edge rows each.
// qattn_kernel: per (b,n): Q proj in-kernel (x -> LDS -> reg A-frags),
//               M^T = sum(3 C) - rank-1 edges, O = Q * M.

#define B_ 8
#define S_ 8192
#define LDW 136   // padded leading dim (shorts) for 128-wide tiles
#define LDT 264   // padded leading dim (shorts) for 256-wide K^T/V^T tiles

using bf16x8 = __attribute__((ext_vector_type(8))) short;   // 8 bf16 = 4 VGPRs
using s16x4  = __attribute__((ext_vector_type(4))) short;
using f32x16 = __attribute__((ext_vector_type(16))) float;

__device__ __forceinline__ short f2bf(float f) {
  union { float f; uint32_t u; } v; v.f = f;
  uint32_t r = v.u + 0x7fffu + ((v.u >> 16) & 1u);   // RNE
  return (short)(r >> 16);
}
__device__ __forceinline__ float bf2f(short s) {
  union { uint32_t u; float f; } v; v.u = ((uint32_t)(uint16_t)s) << 16;
  return v.f;
}

// ---------------------------------------------------------------------------
// kv_kernel: 256 blocks (b,n) x 512 threads (8 waves), 256 rows per block.
// LDS: bufK + bufV = 2 * 128*264*2B = 132 KB (gfx950 allows up to 160 KB/WG).
// ---------------------------------------------------------------------------
__global__ __launch_bounds__(512) void kv_kernel(
    const float* __restrict__ x,
    const float* __restrict__ Wk, const float* __restrict__ bk,
    const float* __restrict__ Wv, const float* __restrict__ bv,
    float* __restrict__ Cpart, short* __restrict__ kedge,
    short* __restrict__ vedge)
{
  __shared__ short bufK[128 * LDT];   // 67,584 B: Wk stage -> K^T tile [d][s]
  __shared__ short bufV[128 * LDT];   // 67,584 B: Wv stage -> V^T tile [h][s]

  const int tid  = threadIdx.x;
  const int lane = tid & 63;
  const int wv   = tid >> 6;        // 0..7
  const int c    = lane & 31;
  const int hl   = lane >> 5;
  const int r0   = blockIdx.x * 256;
  const int b    = r0 >> 13;
  const int n    = (r0 & (S_ - 1)) >> 8;

  // A fragments from x: A[m=c][k=16*kst+8*hl+j], m-row = r0 + wv*32 + c
  bf16x8 afrag[8];
  {
    const float* xrow = x + (size_t)(r0 + wv * 32 + c) * 128 + hl * 8;
    #pragma unroll
    for (int kst = 0; kst < 8; ++kst) {
      const float4* p = (const float4*)(xrow + kst * 16);
      float4 f0 = p[0], f1 = p[1];
      bf16x8 a;
      a[0] = f2bf(f0.x); a[1] = f2bf(f0.y); a[2] = f2bf(f0.z); a[3] = f2bf(f0.w);
      a[4] = f2bf(f1.x); a[5] = f2bf(f1.y); a[6] = f2bf(f1.z); a[7] = f2bf(f1.w);
      afrag[kst] = a;
    }
  }

  auto stageW = [&](const float* W, short* wl) {   // 128x128 f32 -> bf16, LDW rows
    #pragma unroll
    for (int it = 0; it < 8; ++it) {
      int l  = it * 512 + tid;
      int nn = l >> 5;
      int k4 = (l & 31) << 2;
      const float4 f = *(const float4*)(W + nn * 128 + k4);
      s16x4 o;
      o[0] = f2bf(f.x); o[1] = f2bf(f.y); o[2] = f2bf(f.z); o[3] = f2bf(f.w);
      *(s16x4*)(wl + nn * LDW + k4) = o;
    }
  };

  auto gemm = [&](const float* bias, f32x16* acc, const short* wl) {
    #pragma unroll
    for (int nt = 0; nt < 4; ++nt) {
      float bvv = bias[nt * 32 + c];
      #pragma unroll
      for (int i = 0; i < 16; ++i) acc[nt][i] = bvv;
    }
    #pragma unroll
    for (int kst = 0; kst < 8; ++kst) {
      #pragma unroll
      for (int nt = 0; nt < 4; ++nt) {
        bf16x8 bb = *(const bf16x8*)(wl + (nt * 32 + c) * LDW + kst * 16 + hl * 8);
        acc[nt] = __builtin_amdgcn_mfma_f32_32x32x16_bf16(afrag[kst], bb, acc[nt], 0, 0, 0);
      }
    }
  };

  // C-tile layout: col=lane&31, row=(reg&3)+8*(reg>>2)+4*hl
  auto writeTransposedLDS = [&](f32x16* acc, short* wl) {   // wl[d][s], LDT rows
    #pragma unroll
    for (int nt = 0; nt < 4; ++nt) {
      int d = nt * 32 + c;
      #pragma unroll
      for (int g = 0; g < 4; ++g) {
        #pragma unroll
        for (int p = 0; p < 2; ++p) {
          int reg = g * 4 + p * 2;
          int sl  = wv * 32 + g * 8 + hl * 4 + p * 2;   // 0..255
          uint32_t pk = (uint32_t)(uint16_t)f2bf(acc[nt][reg]) |
                        ((uint32_t)(uint16_t)f2bf(acc[nt][reg + 1]) << 16);
          *(uint32_t*)(wl + d * LDT + sl) = pk;
        }
      }
    }
  };

  // ---- K ----
  stageW(Wk, bufK);
  __syncthreads();
  {
    f32x16 acc[4];
    gemm(bk, acc, bufK);
    __syncthreads();                 // all waves done reading Wk
    writeTransposedLDS(acc, bufK);   // K^T -> bufK
    stageW(Wv, bufV);                // disjoint buffer, overlap with transpose
  }
  __syncthreads();

  // ---- V ----
  {
    f32x16 acc[4];
    gemm(bv, acc, bufV);
    __syncthreads();                 // all waves done reading Wv
    writeTransposedLDS(acc, bufV);   // V^T -> bufV
  }
  __syncthreads();

  // ---- C-GEMM: C^T[h][d] = sum_{s=0..255} V^T[h][s] * K^T[d][s] ----
  // Wave grid: ht = wv>>1 (4 x 32 h-rows), dh = wv&1 (2 x 64 d-cols).
  {
    const int ht = wv >> 1;
    const int dh = wv & 1;
    f32x16 cacc[2];
    #pragma unroll
    for (int t = 0; t < 2; ++t)
      #pragma unroll
      for (int i = 0; i < 16; ++i) cacc[t][i] = 0.f;

    #pragma unroll
    for (int kst = 0; kst < 16; ++kst) {
      bf16x8 a  = *(const bf16x8*)(bufV + (ht * 32 + c) * LDT + kst * 16 + hl * 8);
      bf16x8 b0 = *(const bf16x8*)(bufK + (dh * 64 + c) * LDT + kst * 16 + hl * 8);
      bf16x8 b1 = *(const bf16x8*)(bufK + (dh * 64 + 32 + c) * LDT + kst * 16 + hl * 8);
      cacc[0] = __builtin_amdgcn_mfma_f32_32x32x16_bf16(a, b0, cacc[0], 0, 0, 0);
      cacc[1] = __builtin_amdgcn_mfma_f32_32x32x16_bf16(a, b1, cacc[1], 0, 0, 0);
    }

    // edge rows: slot0 = key n*256 (tile col 0), slot1 = key n*256+255 (col 255)
    {
      size_t eo = ((size_t)(b * 32 + n)) * 256;
      if (tid < 128)      kedge[eo + tid]               = bufK[tid * LDT + 0];
      else if (tid < 256) kedge[eo + 128 + (tid - 128)] = bufK[(tid - 128) * LDT + 255];
      else if (tid < 384) vedge[eo + (tid - 256)]       = bufV[(tid - 256) * LDT + 0];
      else                vedge[eo + 128 + (tid - 384)] = bufV[(tid - 384) * LDT + 255];
    }

    float* Cp = Cpart + ((size_t)(b * 32 + n)) * 16384;   // [h][d] row-major
    #pragma unroll
    for (int t = 0; t < 2; ++t) {
      #pragma unroll
      for (int reg = 0; reg < 16; ++reg) {
        int row = (reg & 3) + 8 * (reg >> 2) + 4 * hl;
        Cp[(ht * 32 + row) * 128 + dh * 64 + t * 32 + c] = cacc[t][reg];
      }
    }
  }
}

// ---------------------------------------------------------------------------
// qattn_kernel: 256 blocks (b,n) x 512 threads (8 waves).
// Q proj in-kernel (x -> MFMA -> LDS transpose -> reg A-frags); phase A sums
// 3 C blocks (coalesced f32) minus rank-1 edges; phase B O = Q*M unchanged.
// LDS: 71,680 B (Q tile 69,632 aliased over m_l 34,816 | opat 36,864).
// ---------------------------------------------------------------------------
__global__ __launch_bounds__(512) void qattn_kernel(
    const float* __restrict__ x,
    const float* __restrict__ Wq, const float* __restrict__ bq,
    const float* __restrict__ Cpart,
    const short* __restrict__ kedge, const short* __restrict__ vedge,
    float* __restrict__ out)
{
  __shared__ __align__(16) char smem[71680];
  short* q_l  = (short*)smem;            // Wq stage [128][LDW], then Q tile [256][LDW]
  short* m_l  = (short*)smem;            // [128][LDW] after Q tile dead
  float* opat = (float*)(smem + 34816);  // 8 waves * 32*36 f32

  const int tid  = threadIdx.x;
  const int lane = tid & 63;
  const int wv   = tid >> 6;
  const int c    = lane & 31;
  const int hl   = lane >> 5;
  const int r0   = blockIdx.x * 256;
  const int b    = r0 >> 13;
  const int n    = (r0 & (S_ - 1)) >> 8;

  // A fragments from x (Q rows)
  bf16x8 afrag[8];
  {
    const float* xrow = x + (size_t)(r0 + wv * 32 + c) * 128 + hl * 8;
    #pragma unroll
    for (int kst = 0; kst < 8; ++kst) {
      const float4* p = (const float4*)(xrow + kst * 16);
      float4 f0 = p[0], f1 = p[1];
      bf16x8 a;
      a[0] = f2bf(f0.x); a[1] = f2bf(f0.y); a[2] = f2bf(f0.z); a[3] = f2bf(f0.w);
      a[4] = f2bf(f1.x); a[5] = f2bf(f1.y); a[6] = f2bf(f1.z); a[7] = f2bf(f1.w);
      afrag[kst] = a;
    }
  }

  // stage Wq
  #pragma unroll
  for (int it = 0; it < 8; ++it) {
    int l  = it * 512 + tid;
    int nn = l >> 5;
    int k4 = (l & 31) << 2;
    const float4 f = *(const float4*)(Wq + nn * 128 + k4);
    s16x4 o;
    o[0] = f2bf(f.x); o[1] = f2bf(f.y); o[2] = f2bf(f.z); o[3] = f2bf(f.w);
    *(s16x4*)(q_l + nn * LDW + k4) = o;
  }
  __syncthreads();

  // Q GEMM
  f32x16 qacc[4];
  #pragma unroll
  for (int nt = 0; nt < 4; ++nt) {
    float bvv = bq[nt * 32 + c];
    #pragma unroll
    for (int i = 0; i < 16; ++i) qacc[nt][i] = bvv;
  }
  #pragma unroll
  for (int kst = 0; kst < 8; ++kst) {
    #pragma unroll
    for (int nt = 0; nt < 4; ++nt) {
      bf16x8 bb = *(const bf16x8*)(q_l + (nt * 32 + c) * LDW + kst * 16 + hl * 8);
      qacc[nt] = __builtin_amdgcn_mfma_f32_32x32x16_bf16(afrag[kst], bb, qacc[nt], 0, 0, 0);
    }
  }
  __syncthreads();   // done reading Wq

  // Q tile [s][d] bf16 (rows 0..255)
  #pragma unroll
  for (int nt = 0; nt < 4; ++nt) {
    #pragma unroll
    for (int reg = 0; reg < 16; ++reg) {
      int row = (reg & 3) + 8 * (reg >> 2) + 4 * hl;
      q_l[(wv * 32 + row) * LDW + nt * 32 + c] = f2bf(qacc[nt][reg]);
    }
  }
  __syncthreads();

  // Q A-frags to regs; wave wv owns rows 32wv..+32
  bf16x8 qf[8];
  #pragma unroll
  for (int kst = 0; kst < 8; ++kst)
    qf[kst] = *(const bf16x8*)(q_l + (wv * 32 + c) * LDW + kst * 16 + hl * 8);

  // ---- phase A (global + regs only; overlaps the Q-tile drain) ----
  float m[32];
  #pragma unroll
  for (int i = 0; i < 32; ++i) m[i] = 0.f;

  const float* Cb0 = Cpart + (size_t)b * 32 * 16384;
  #pragma unroll
  for (int e = 0; e < 3; ++e) {
    int nn = n - 1 + e;
    if (nn < 0 || nn > 31) continue;          // wave-uniform branch
    const float4* Cp = (const float4*)(Cb0 + (size_t)nn * 16384);
    #pragma unroll
    for (int i4 = 0; i4 < 8; ++i4) {
      float4 f = Cp[i4 * 512 + tid];
      m[i4 * 4 + 0] += f.x; m[i4 * 4 + 1] += f.y;
      m[i4 * 4 + 2] += f.z; m[i4 * 4 + 3] += f.w;
    }
  }

  const int d0 = (tid & 31) << 2;
  if (n > 0) {   // subtract key a = (n-1)*256  (slot 0 of block n-1)
    const short* ke = kedge + ((size_t)(b * 32 + n - 1)) * 256;
    const short* ve = vedge + ((size_t)(b * 32 + n - 1)) * 256;
    float k0 = bf2f(ke[d0]),     k1 = bf2f(ke[d0 + 1]);
    float k2 = bf2f(ke[d0 + 2]), k3 = bf2f(ke[d0 + 3]);
    #pragma unroll
    for (int i4 = 0; i4 < 8; ++i4) {
      float vs = bf2f(ve[i4 * 16 + (tid >> 5)]);
      m[i4 * 4 + 0] -= vs * k0; m[i4 * 4 + 1] -= vs * k1;
      m[i4 * 4 + 2] -= vs * k2; m[i4 * 4 + 3] -= vs * k3;
    }
  }
  if (n < 31) {  // subtract key z = (n+1)*256+255  (slot 1 of block n+1)
    const short* ke = kedge + ((size_t)(b * 32 + n + 1)) * 256 + 128;
    const short* ve = vedge + ((size_t)(b * 32 + n + 1)) * 256 + 128;
    float k0 = bf2f(ke[d0]),     k1 = bf2f(ke[d0 + 1]);
    float k2 = bf2f(ke[d0 + 2]), k3 = bf2f(ke[d0 + 3]);
    #pragma unroll
    for (int i4 = 0; i4 < 8; ++i4) {
      float vs = bf2f(ve[i4 * 16 + (tid >> 5)]);
      m[i4 * 4 + 0] -= vs * k0; m[i4 * 4 + 1] -= vs * k1;
      m[i4 * 4 + 2] -= vs * k2; m[i4 * 4 + 3] -= vs * k3;
    }
  }
  __syncthreads();   // all Q-tile reads (qf) done before m_l overwrites it

  const float scale = 0.08838834764831845f;   // 1/sqrt(128)
  #pragma unroll
  for (int i4 = 0; i4 < 8; ++i4) {
    int h = i4 * 16 + (tid >> 5);
    s16x4 o;
    o[0] = f2bf(m[i4 * 4 + 0] * scale); o[1] = f2bf(m[i4 * 4 + 1] * scale);
    o[2] = f2bf(m[i4 * 4 + 2] * scale); o[3] = f2bf(m[i4 * 4 + 3] * scale);
    *(s16x4*)(m_l + h * LDW + d0) = o;
  }
  __syncthreads();

  // ---- phase B: O = Q * M; wave wv owns 32 q-rows [n*256+32wv, +32) ----
  f32x16 oacc[4];
  #pragma unroll
  for (int nt = 0; nt < 4; ++nt)
    #pragma unroll
    for (int i = 0; i < 16; ++i) oacc[nt][i] = 0.f;

  #pragma unroll
  for (int kst = 0; kst < 8; ++kst) {
    #pragma unroll
    for (int nt = 0; nt < 4; ++nt) {
      bf16x8 bb = *(const bf16x8*)(m_l + (nt * 32 + c) * LDW + kst * 16 + hl * 8);
      oacc[nt] = __builtin_amdgcn_mfma_f32_32x32x16_bf16(qf[kst], bb, oacc[nt], 0, 0, 0);
    }
  }

  // epilogue: per-wave LDS patch (32x36 f32) -> coalesced float4 stores
  float* patch = opat + wv * (32 * 36);
  float* outb  = out + ((size_t)b * S_ + n * 256 + wv * 32) * 128;
  #pragma unroll
  for (int nt = 0; nt < 4; ++nt) {
    #pragma unroll
    for (int reg = 0; reg < 16; ++reg) {
      int row = (reg & 3) + 8 * (reg >> 2) + 4 * hl;
      patch[row * 36 + c] = oacc[nt][reg];
    }
    #pragma unroll
    for (int p = 0; p < 4; ++p) {
      int row = p * 8 + (lane >> 3);
      float4 vv = *(const float4*)(patch + row * 36 + (lane & 7) * 4);
      *(float4*)(outb + (size_t)row * 128 + nt * 32 + (lane & 7) * 4) = vv;
    }
  }
}

// ---------------------------------------------------------------------------
extern "C" void kernel_launch(void* const* d_in, const int* in_sizes, int n_in,
                              void* d_out, int out_size, void* d_ws, size_t ws_size,
                              hipStream_t stream) {
  const float* x  = (const float*)d_in[0];
  const float* Wq = (const float*)d_in[1];
  const float* bq = (const float*)d_in[2];
  const float* Wk = (const float*)d_in[3];
  const float* bk = (const float*)d_in[4];
  const float* Wv = (const float*)d_in[5];
  const float* bv = (const float*)d_in[6];
  float* out = (float*)d_out;

  float* Cpart = (float*)d_ws;                          // 8*32*128*128 f32 = 16.8MB
  short* kedge = (short*)(Cpart + (size_t)8 * 32 * 16384);
  short* vedge = kedge + (size_t)8 * 32 * 256;

  kv_kernel<<<256, 512, 0, stream>>>(x, Wk, bk, Wv, bv, Cpart, kedge, vedge);
  qattn_kernel<<<256, 512, 0, stream>>>(x, Wq, bq, Cpart, kedge, vedge, out);
}

// Round 5
// 118.514 us; speedup vs baseline: 1.1440x; 1.0157x over previous
//
#include <hip/hip_runtime.h>
#include <stdint.h>

// BlockAttention: B=8, S=8192, D=H=128, BLOCK=256, WINDOW=256 (halo 255, W=766)
// No softmax => out_blk = Q_blk @ (scale * M_n),  M_n = K_win^T V_win.
// Full-block decomposition:
//   M_n^T = C_{n-1}^T + C_n^T + C_{n+1}^T - v_a(x)k_a - v_z(x)k_z
//   C_m^T[h][d] = sum over block m's 256 keys of v[h]*k[d]  (f32)
//   a = (n-1)*256 (slot0 of block n-1), z = (n+1)*256+255 (slot1 of block n+1).
// kv_kernel: per (b,n): x read ONCE -> afrag regs; Q proj -> qb (bf16, via LDS
//            transpose); K/V proj (LDS tiles only); C_n^T GEMM; edges.
// attn_kernel: qf from qb; M^T = sum(3 C, coalesced f32) - rank-1 edges;
//            O = Q * M. No x, no weights, 1 barrier.

#define B_ 8
#define S_ 8192
#define LDW 136   // padded leading dim (shorts) for 128-wide tiles
#define LDT 264   // padded leading dim (shorts) for 256-wide K^T/V^T tiles

using bf16x8 = __attribute__((ext_vector_type(8))) short;   // 8 bf16 = 4 VGPRs
using s16x4  = __attribute__((ext_vector_type(4))) short;
using f32x16 = __attribute__((ext_vector_type(16))) float;

__device__ __forceinline__ short f2bf(float f) {
  union { float f; uint32_t u; } v; v.f = f;
  uint32_t r = v.u + 0x7fffu + ((v.u >> 16) & 1u);   // RNE
  return (short)(r >> 16);
}
__device__ __forceinline__ float bf2f(short s) {
  union { uint32_t u; float f; } v; v.u = ((uint32_t)(uint16_t)s) << 16;
  return v.f;
}

// ---------------------------------------------------------------------------
// kv_kernel: 256 blocks (b,n) x 512 threads (8 waves), 256 rows per block.
// LDS regions: A = 69,632 B (Wq stage / Q tile [256][LDW] / K^T [128][LDT])
//              B = 67,584 B (Wk,Wv stage / V^T [128][LDT]);  total 137,216 B.
// ---------------------------------------------------------------------------
__global__ __launch_bounds__(512) void kv_kernel(
    const float* __restrict__ x,
    const float* __restrict__ Wq, const float* __restrict__ bq,
    const float* __restrict__ Wk, const float* __restrict__ bk,
    const float* __restrict__ Wv, const float* __restrict__ bv,
    short* __restrict__ qb, float* __restrict__ Cpart,
    short* __restrict__ kedge, short* __restrict__ vedge)
{
  __shared__ __align__(16) char smem[137216];
  short* rgA = (short*)smem;             // 69,632 B
  short* rgB = (short*)(smem + 69632);   // 67,584 B

  const int tid  = threadIdx.x;
  const int lane = tid & 63;
  const int wv   = tid >> 6;        // 0..7
  const int c    = lane & 31;
  const int hl   = lane >> 5;
  const int r0   = blockIdx.x * 256;
  const int b    = r0 >> 13;
  const int n    = (r0 & (S_ - 1)) >> 8;

  // A fragments from x: A[m=c][k=16*kst+8*hl+j], m-row = r0 + wv*32 + c
  bf16x8 afrag[8];
  {
    const float* xrow = x + (size_t)(r0 + wv * 32 + c) * 128 + hl * 8;
    #pragma unroll
    for (int kst = 0; kst < 8; ++kst) {
      const float4* p = (const float4*)(xrow + kst * 16);
      float4 f0 = p[0], f1 = p[1];
      bf16x8 a;
      a[0] = f2bf(f0.x); a[1] = f2bf(f0.y); a[2] = f2bf(f0.z); a[3] = f2bf(f0.w);
      a[4] = f2bf(f1.x); a[5] = f2bf(f1.y); a[6] = f2bf(f1.z); a[7] = f2bf(f1.w);
      afrag[kst] = a;
    }
  }

  auto stageW = [&](const float* W, short* wl) {   // 128x128 f32 -> bf16, LDW rows
    #pragma unroll
    for (int it = 0; it < 8; ++it) {
      int l  = it * 512 + tid;
      int nn = l >> 5;
      int k4 = (l & 31) << 2;
      const float4 f = *(const float4*)(W + nn * 128 + k4);
      s16x4 o;
      o[0] = f2bf(f.x); o[1] = f2bf(f.y); o[2] = f2bf(f.z); o[3] = f2bf(f.w);
      *(s16x4*)(wl + nn * LDW + k4) = o;
    }
  };

  auto gemm = [&](const float* bias, f32x16* acc, const short* wl) {
    #pragma unroll
    for (int nt = 0; nt < 4; ++nt) {
      float bvv = bias[nt * 32 + c];
      #pragma unroll
      for (int i = 0; i < 16; ++i) acc[nt][i] = bvv;
    }
    #pragma unroll
    for (int kst = 0; kst < 8; ++kst) {
      #pragma unroll
      for (int nt = 0; nt < 4; ++nt) {
        bf16x8 bb = *(const bf16x8*)(wl + (nt * 32 + c) * LDW + kst * 16 + hl * 8);
        acc[nt] = __builtin_amdgcn_mfma_f32_32x32x16_bf16(afrag[kst], bb, acc[nt], 0, 0, 0);
      }
    }
  };

  // C-tile layout: col=lane&31, row=(reg&3)+8*(reg>>2)+4*hl
  auto writeTransposedLDS = [&](f32x16* acc, short* wl) {   // wl[d][s], LDT rows
    #pragma unroll
    for (int nt = 0; nt < 4; ++nt) {
      int d = nt * 32 + c;
      #pragma unroll
      for (int g = 0; g < 4; ++g) {
        #pragma unroll
        for (int p = 0; p < 2; ++p) {
          int reg = g * 4 + p * 2;
          int sl  = wv * 32 + g * 8 + hl * 4 + p * 2;   // 0..255
          uint32_t pk = (uint32_t)(uint16_t)f2bf(acc[nt][reg]) |
                        ((uint32_t)(uint16_t)f2bf(acc[nt][reg + 1]) << 16);
          *(uint32_t*)(wl + d * LDT + sl) = pk;
        }
      }
    }
  };

  // ---- phase 1: Q GEMM ----
  stageW(Wq, rgA);
  __syncthreads();
  f32x16 qacc[4];
  gemm(bq, qacc, rgA);
  __syncthreads();                   // all waves done reading Wq from rgA

  // ---- phase 2: Q tile [s][d] bf16 -> rgA; Wk -> rgB ----
  #pragma unroll
  for (int nt = 0; nt < 4; ++nt) {
    #pragma unroll
    for (int reg = 0; reg < 16; ++reg) {
      int row = (reg & 3) + 8 * (reg >> 2) + 4 * hl;
      rgA[(wv * 32 + row) * LDW + nt * 32 + c] = f2bf(qacc[nt][reg]);
    }
  }
  stageW(Wk, rgB);
  __syncthreads();

  // ---- phase 3: qb store (reads rgA) + K GEMM (reads rgB) ----
  #pragma unroll
  for (int it = 0; it < 8; ++it) {
    int l  = it * 512 + tid;
    int s  = l >> 4;
    int d8 = (l & 15) << 3;
    bf16x8 vvv = *(const bf16x8*)(rgA + s * LDW + d8);
    *(bf16x8*)(qb + (size_t)(r0 + s) * 128 + d8) = vvv;
  }
  f32x16 kacc[4];
  gemm(bk, kacc, rgB);
  __syncthreads();                   // qb LDS reads + Wk reads done

  // ---- phase 4: K^T -> rgA; Wv -> rgB ----
  writeTransposedLDS(kacc, rgA);
  stageW(Wv, rgB);
  __syncthreads();

  // ---- phase 5: V GEMM ----
  f32x16 vacc[4];
  gemm(bv, vacc, rgB);
  __syncthreads();                   // done reading Wv from rgB

  // ---- phase 6: V^T -> rgB ----
  writeTransposedLDS(vacc, rgB);
  __syncthreads();

  // ---- phase 7: C-GEMM: C^T[h][d] = sum_{s=0..255} V^T[h][s]*K^T[d][s] ----
  {
    const int ht = wv >> 1;          // 4 x 32 h-rows
    const int dh = wv & 1;           // 2 x 64 d-cols
    f32x16 cacc[2];
    #pragma unroll
    for (int t = 0; t < 2; ++t)
      #pragma unroll
      for (int i = 0; i < 16; ++i) cacc[t][i] = 0.f;

    #pragma unroll
    for (int kst = 0; kst < 16; ++kst) {
      bf16x8 a  = *(const bf16x8*)(rgB + (ht * 32 + c) * LDT + kst * 16 + hl * 8);
      bf16x8 b0 = *(const bf16x8*)(rgA + (dh * 64 + c) * LDT + kst * 16 + hl * 8);
      bf16x8 b1 = *(const bf16x8*)(rgA + (dh * 64 + 32 + c) * LDT + kst * 16 + hl * 8);
      cacc[0] = __builtin_amdgcn_mfma_f32_32x32x16_bf16(a, b0, cacc[0], 0, 0, 0);
      cacc[1] = __builtin_amdgcn_mfma_f32_32x32x16_bf16(a, b1, cacc[1], 0, 0, 0);
    }

    // edge rows: slot0 = key n*256 (tile col 0), slot1 = key n*256+255 (col 255)
    {
      size_t eo = ((size_t)(b * 32 + n)) * 256;
      if (tid < 128)      kedge[eo + tid]               = rgA[tid * LDT + 0];
      else if (tid < 256) kedge[eo + 128 + (tid - 128)] = rgA[(tid - 128) * LDT + 255];
      else if (tid < 384) vedge[eo + (tid - 256)]       = rgB[(tid - 256) * LDT + 0];
      else                vedge[eo + 128 + (tid - 384)] = rgB[(tid - 384) * LDT + 255];
    }

    float* Cp = Cpart + ((size_t)(b * 32 + n)) * 16384;   // [h][d] row-major
    #pragma unroll
    for (int t = 0; t < 2; ++t) {
      #pragma unroll
      for (int reg = 0; reg < 16; ++reg) {
        int row = (reg & 3) + 8 * (reg >> 2) + 4 * hl;
        Cp[(ht * 32 + row) * 128 + dh * 64 + t * 32 + c] = cacc[t][reg];
      }
    }
  }
}

// ---------------------------------------------------------------------------
// attn_kernel: 256 blocks (b,n) x 512 threads (8 waves). No x, no weights.
// Phase A: M^T[h][d] = scale*(sum 3 C blocks - v_a[h]k_a[d] - v_z[h]k_z[d]),
//   thread owns h = i4*16 + (tid>>5), d = (tid&31)*4..+3 (coalesced float4).
// Phase B: O = Q * M, qf straight from qb. One barrier total.
// LDS: m_l 34,816 + opat 36,864 = 71,680 B.
// ---------------------------------------------------------------------------
__global__ __launch_bounds__(512) void attn_kernel(
    const short* __restrict__ qb, const float* __restrict__ Cpart,
    const short* __restrict__ kedge, const short* __restrict__ vedge,
    float* __restrict__ out)
{
  __shared__ __align__(16) short m_l[128 * LDW];      // 34.8 KB
  __shared__ __align__(16) float opat[8 * 32 * 36];   // 36.9 KB

  const int tid  = threadIdx.x;
  const int lane = tid & 63;
  const int wv   = tid >> 6;
  const int c    = lane & 31;
  const int hl   = lane >> 5;
  const int r0   = blockIdx.x * 256;
  const int b    = r0 >> 13;
  const int n    = (r0 & (S_ - 1)) >> 8;

  // ---- phase A ----
  float m[32];
  #pragma unroll
  for (int i = 0; i < 32; ++i) m[i] = 0.f;

  const float* Cb0 = Cpart + (size_t)b * 32 * 16384;
  #pragma unroll
  for (int e = 0; e < 3; ++e) {
    int nn = n - 1 + e;
    if (nn < 0 || nn > 31) continue;          // wave-uniform branch
    const float4* Cp = (const float4*)(Cb0 + (size_t)nn * 16384);
    #pragma unroll
    for (int i4 = 0; i4 < 8; ++i4) {
      float4 f = Cp[i4 * 512 + tid];
      m[i4 * 4 + 0] += f.x; m[i4 * 4 + 1] += f.y;
      m[i4 * 4 + 2] += f.z; m[i4 * 4 + 3] += f.w;
    }
  }

  const int d0 = (tid & 31) << 2;
  if (n > 0) {   // subtract key a = (n-1)*256  (slot 0 of block n-1)
    const short* ke = kedge + ((size_t)(b * 32 + n - 1)) * 256;
    const short* ve = vedge + ((size_t)(b * 32 + n - 1)) * 256;
    float k0 = bf2f(ke[d0]),     k1 = bf2f(ke[d0 + 1]);
    float k2 = bf2f(ke[d0 + 2]), k3 = bf2f(ke[d0 + 3]);
    #pragma unroll
    for (int i4 = 0; i4 < 8; ++i4) {
      float vs = bf2f(ve[i4 * 16 + (tid >> 5)]);
      m[i4 * 4 + 0] -= vs * k0; m[i4 * 4 + 1] -= vs * k1;
      m[i4 * 4 + 2] -= vs * k2; m[i4 * 4 + 3] -= vs * k3;
    }
  }
  if (n < 31) {  // subtract key z = (n+1)*256+255  (slot 1 of block n+1)
    const short* ke = kedge + ((size_t)(b * 32 + n + 1)) * 256 + 128;
    const short* ve = vedge + ((size_t)(b * 32 + n + 1)) * 256 + 128;
    float k0 = bf2f(ke[d0]),     k1 = bf2f(ke[d0 + 1]);
    float k2 = bf2f(ke[d0 + 2]), k3 = bf2f(ke[d0 + 3]);
    #pragma unroll
    for (int i4 = 0; i4 < 8; ++i4) {
      float vs = bf2f(ve[i4 * 16 + (tid >> 5)]);
      m[i4 * 4 + 0] -= vs * k0; m[i4 * 4 + 1] -= vs * k1;
      m[i4 * 4 + 2] -= vs * k2; m[i4 * 4 + 3] -= vs * k3;
    }
  }

  const float scale = 0.08838834764831845f;   // 1/sqrt(128)
  #pragma unroll
  for (int i4 = 0; i4 < 8; ++i4) {
    int h = i4 * 16 + (tid >> 5);
    s16x4 o;
    o[0] = f2bf(m[i4 * 4 + 0] * scale); o[1] = f2bf(m[i4 * 4 + 1] * scale);
    o[2] = f2bf(m[i4 * 4 + 2] * scale); o[3] = f2bf(m[i4 * 4 + 3] * scale);
    *(s16x4*)(m_l + h * LDW + d0) = o;
  }

  // Q A-frags from qb (global; issued before the barrier to hide latency)
  bf16x8 qf[8];
  {
    const short* q0p = qb + (size_t)(r0 + wv * 32 + c) * 128 + hl * 8;
    #pragma unroll
    for (int kst = 0; kst < 8; ++kst) qf[kst] = *(const bf16x8*)(q0p + kst * 16);
  }
  __syncthreads();

  // ---- phase B: O = Q * M; wave wv owns 32 q-rows [n*256+32wv, +32) ----
  f32x16 oacc[4];
  #pragma unroll
  for (int nt = 0; nt < 4; ++nt)
    #pragma unroll
    for (int i = 0; i < 16; ++i) oacc[nt][i] = 0.f;

  #pragma unroll
  for (int kst = 0; kst < 8; ++kst) {
    #pragma unroll
    for (int nt = 0; nt < 4; ++nt) {
      bf16x8 bb = *(const bf16x8*)(m_l + (nt * 32 + c) * LDW + kst * 16 + hl * 8);
      oacc[nt] = __builtin_amdgcn_mfma_f32_32x32x16_bf16(qf[kst], bb, oacc[nt], 0, 0, 0);
    }
  }

  // epilogue: per-wave LDS patch (32x36 f32) -> coalesced float4 stores
  float* patch = opat + wv * (32 * 36);
  float* outb  = out + ((size_t)b * S_ + n * 256 + wv * 32) * 128;
  #pragma unroll
  for (int nt = 0; nt < 4; ++nt) {
    #pragma unroll
    for (int reg = 0; reg < 16; ++reg) {
      int row = (reg & 3) + 8 * (reg >> 2) + 4 * hl;
      patch[row * 36 + c] = oacc[nt][reg];
    }
    #pragma unroll
    for (int p = 0; p < 4; ++p) {
      int row = p * 8 + (lane >> 3);
      float4 vv = *(const float4*)(patch + row * 36 + (lane & 7) * 4);
      *(float4*)(outb + (size_t)row * 128 + nt * 32 + (lane & 7) * 4) = vv;
    }
  }
}

// ---------------------------------------------------------------------------
extern "C" void kernel_launch(void* const* d_in, const int* in_sizes, int n_in,
                              void* d_out, int out_size, void* d_ws, size_t ws_size,
                              hipStream_t stream) {
  const float* x  = (const float*)d_in[0];
  const float* Wq = (const float*)d_in[1];
  const float* bq = (const float*)d_in[2];
  const float* Wk = (const float*)d_in[3];
  const float* bk = (const float*)d_in[4];
  const float* Wv = (const float*)d_in[5];
  const float* bv = (const float*)d_in[6];
  float* out = (float*)d_out;

  float* Cpart = (float*)d_ws;                          // 8*32*128*128 f32 = 16.8MB
  short* kedge = (short*)(Cpart + (size_t)8 * 32 * 16384);
  short* vedge = kedge + (size_t)8 * 32 * 256;
  short* qb    = vedge + (size_t)8 * 32 * 256;          // 16.8MB bf16 [b][s][d]

  kv_kernel<<<256, 512, 0, stream>>>(x, Wq, bq, Wk, bk, Wv, bv,
                                     qb, Cpart, kedge, vedge);
  attn_kernel<<<256, 512, 0, stream>>>(qb, Cpart, kedge, vedge, out);
}